// Round 6
// baseline (365.742 us; speedup 1.0000x reference)
//
#include <hip/hip_runtime.h>

typedef __attribute__((ext_vector_type(4))) float f32x4;

#define NT 256
#define S 10
#define SL 5                    // corpus rows per lane (2 lanes per batch row)
#define D 100
#define H 16
#define NITER 5
#define RPB (NT / 2)            // batch rows per block = 128
#define RQ 25                   // LDS out-staging row stride in quads (24 + 1 pad)
#define OUTQ 24                 // quads per output row (6*16 floats)

// launch_bounds(,1): full 256-VGPR budget. Per-lane algorithmic state is only
// ~96 f32 (ic[5][4]+usum+temps), so even with aggressive load scheduling the
// allocator stays under 256 -> no scratch spill (r3 spilled ONLY because
// (,2) forced a 128 budget). 256 VGPR still allows 2 waves/SIMD = the grid's
// occupancy (512 blocks x 4 waves / 1024 SIMDs).
__global__ __launch_bounds__(NT, 1)
void attn_greedy_kernel(const float* __restrict__ user_intent,
                        const float* __restrict__ item_corpus,
                        const float* __restrict__ W_proj,
                        const float* __restrict__ b_proj,
                        const float* __restrict__ W_k,
                        const float* __restrict__ b_k,
                        float* __restrict__ out)
{
    // Weights: wave-uniform broadcast reads (conflict-free).
    __shared__ f32x4 s_wp[D * 4];          // wp[d][q]  6400 B
    __shared__ f32x4 s_wk[H * 4];          // wk[k][q]  1024 B
    __shared__ f32x4 s_bp[4];
    __shared__ f32x4 s_bk[4];
    __shared__ f32x4 s_out[RPB * RQ];      // 50 KB out staging

    {
        float* wpf = (float*)s_wp;
        for (int i = threadIdx.x; i < D * H; i += NT) wpf[i] = W_proj[i];
        float* wkf = (float*)s_wk;
        for (int i = threadIdx.x; i < H * H; i += NT) wkf[i] = W_k[i];
        if (threadIdx.x < H) {
            ((float*)s_bp)[threadIdx.x] = b_proj[threadIdx.x];
            ((float*)s_bk)[threadIdx.x] = b_k[threadIdx.x];
        }
    }
    __syncthreads();

    const int t = threadIdx.x;
    const int half = t & 1;                // which 5 corpus rows this lane owns
    const int r = t >> 1;                  // batch row within block
    const size_t b = (size_t)blockIdx.x * RPB + r;

    // This lane streams 5 rows x 400B sequentially (1 live line/lane -> L1-resident).
    const f32x4* chalf = (const f32x4*)item_corpus + b * (S * D / 4) + half * (SL * D / 4);

    // user_intent: both lanes of the pair load the full row (same lines).
    const f32x4* urow = (const f32x4*)user_intent + b * 4;
    f32x4 usum[4];
    #pragma unroll
    for (int q = 0; q < 4; ++q) {
        usum[q] = urow[q];
        if (!half) s_out[r * RQ + q] = usum[q];   // ui[:,0,:]
    }

    // ---- Projection of this lane's 5 rows: ic[ls][:] = sum_d c*Wp[d][:] + bp
    f32x4 ic[SL][4];
    #pragma unroll
    for (int ls = 0; ls < SL; ++ls) {
        f32x4 a0 = s_bp[0], a1 = s_bp[1], a2 = s_bp[2], a3 = s_bp[3];
        #pragma unroll 5
        for (int i = 0; i < D / 4; ++i) {
            f32x4 c = chalf[ls * (D / 4) + i];
            #pragma unroll
            for (int dd = 0; dd < 4; ++dd) {
                float a = c[dd];
                const f32x4* wrow = &s_wp[(i * 4 + dd) * 4];
                a0 += a * wrow[0];
                a1 += a * wrow[1];
                a2 += a * wrow[2];
                a3 += a * wrow[3];
            }
        }
        ic[ls][0] = a0; ic[ls][1] = a1; ic[ls][2] = a2; ic[ls][3] = a3;
    }

    // ---- Greedy iterations
    for (int it = 0; it < NITER; ++it) {
        // ic = ic @ Wk + bk, in place per row (k ascending, as all passing rounds)
        #pragma unroll
        for (int ls = 0; ls < SL; ++ls) {
            f32x4 n0 = s_bk[0], n1 = s_bk[1], n2 = s_bk[2], n3 = s_bk[3];
            #pragma unroll
            for (int k = 0; k < H; ++k) {
                float a = ic[ls][k >> 2][k & 3];
                const f32x4* wrow = &s_wk[k * 4];
                n0 += a * wrow[0];
                n1 += a * wrow[1];
                n2 += a * wrow[2];
                n3 += a * wrow[3];
            }
            ic[ls][0] = n0; ic[ls][1] = n1; ic[ls][2] = n2; ic[ls][3] = n3;
        }

        // src = mean(ui); usum is bit-identical in both lanes of the pair
        float cnt = (float)(it + 1);
        f32x4 src[4];
        #pragma unroll
        for (int q = 0; q < 4; ++q) src[q] = usum[q] / cnt;

        // local scores + first-max argmax over this lane's rows (global s index)
        float best = 0.0f;
        int gidx = half * SL;
        #pragma unroll
        for (int ls = 0; ls < SL; ++ls) {
            float sc = 0.0f;
            #pragma unroll
            for (int q = 0; q < 4; ++q)
                #pragma unroll
                for (int c = 0; c < 4; ++c)
                    sc += ic[ls][q][c] * src[q][c];
            if (ls == 0 || sc > best) { best = sc; gidx = half * SL + ls; }
        }

        // combine across the lane pair: low half wins ties (first-max over s)
        float osc = __shfl_xor(best, 1);
        int oidx = __shfl_xor(gidx, 1);
        float scL = half ? osc : best;
        int   iL  = half ? oidx : gidx;
        float scH = half ? best : osc;
        int   iH  = half ? gidx : oidx;
        int bidx = (scH > scL) ? iH : iL;

        // item_vec: owner lane selects (unrolled, static indexing), partner gets 0,
        // then pair-sum via shuffle -> both lanes hold iv exactly (x+0)
        f32x4 ivl[4];
        #pragma unroll
        for (int q = 0; q < 4; ++q) ivl[q] = f32x4{0.f, 0.f, 0.f, 0.f};
        #pragma unroll
        for (int ls = 0; ls < SL; ++ls) {
            bool take = ((half * SL + ls) == bidx);
            #pragma unroll
            for (int q = 0; q < 4; ++q)
                ivl[q] = take ? ic[ls][q] : ivl[q];
        }
        f32x4 iv[4];
        #pragma unroll
        for (int q = 0; q < 4; ++q) {
            #pragma unroll
            for (int c = 0; c < 4; ++c)
                iv[q][c] = ivl[q][c] + __shfl_xor(ivl[q][c], 1);
        }

        #pragma unroll
        for (int q = 0; q < 4; ++q) {
            usum[q] += iv[q];
            if (!half) s_out[r * RQ + (it + 1) * 4 + q] = iv[q];
        }
    }

    // ---- Coalesced output: 128 rows x 24 quads = contiguous 48KB per block.
    __syncthreads();
    f32x4* out4 = (f32x4*)out;
    const size_t obase = (size_t)blockIdx.x * RPB * OUTQ;
    #pragma unroll
    for (int k = 0; k < OUTQ / 2; ++k) {
        int j = t + k * NT;
        int row = j / OUTQ;
        int q = j - row * OUTQ;
        out4[obase + j] = s_out[row * RQ + q];
    }
}

extern "C" void kernel_launch(void* const* d_in, const int* in_sizes, int n_in,
                              void* d_out, int out_size, void* d_ws, size_t ws_size,
                              hipStream_t stream) {
    const float* user_intent = (const float*)d_in[0];
    const float* item_corpus = (const float*)d_in[1];
    const float* W_proj      = (const float*)d_in[2];
    const float* b_proj      = (const float*)d_in[3];
    const float* W_k         = (const float*)d_in[4];
    const float* b_k         = (const float*)d_in[5];
    float* out = (float*)d_out;

    const int bs = 65536;
    hipLaunchKernelGGL(attn_greedy_kernel,
                       dim3(bs * 2 / NT), dim3(NT), 0, stream,
                       user_intent, item_corpus, W_proj, b_proj, W_k, b_k, out);
}

// Round 7
// 312.364 us; speedup vs baseline: 1.1709x; 1.1709x over previous
//
#include <hip/hip_runtime.h>

typedef __attribute__((ext_vector_type(4))) float f32x4;

#define NT 256
#define S 10
#define SL 5                    // corpus rows per lane in search kernel
#define D 100
#define H 16
#define NITER 5
#define RPB (NT / 2)            // batch rows per block in search kernel = 128
#define RQ 25                   // LDS out-staging row stride in quads (24 + 1 pad)
#define OUTQ 24                 // quads per output row (6*16 floats)
#define WS_NEEDED ((size_t)65536 * S * H * 4)   // 41.9 MB ic buffer

// ================= Kernel A: projection (streaming) =================
// One thread per corpus row (b*10+s == gid): 400B sequential read,
// 64B coalesced write. ~50 live VGPRs -> no spill, high occupancy.
__global__ __launch_bounds__(NT, 1)
void proj_kernel(const float* __restrict__ item_corpus,
                 const float* __restrict__ W_proj,
                 const float* __restrict__ b_proj,
                 float* __restrict__ ic_ws)
{
    __shared__ f32x4 s_wp[D * 4];   // wp[d][q], broadcast reads
    __shared__ f32x4 s_bp[4];
    {
        float* wpf = (float*)s_wp;
        for (int i = threadIdx.x; i < D * H; i += NT) wpf[i] = W_proj[i];
        if (threadIdx.x < H) ((float*)s_bp)[threadIdx.x] = b_proj[threadIdx.x];
    }
    __syncthreads();

    const size_t gid = (size_t)blockIdx.x * NT + threadIdx.x;
    const f32x4* crow = (const f32x4*)item_corpus + gid * (D / 4);

    // Same d-ascending accumulation order as all passing rounds.
    f32x4 a0 = s_bp[0], a1 = s_bp[1], a2 = s_bp[2], a3 = s_bp[3];
    #pragma unroll 5
    for (int i = 0; i < D / 4; ++i) {
        f32x4 c = crow[i];
        #pragma unroll
        for (int dd = 0; dd < 4; ++dd) {
            float a = c[dd];
            const f32x4* wrow = &s_wp[(i * 4 + dd) * 4];
            a0 += a * wrow[0];
            a1 += a * wrow[1];
            a2 += a * wrow[2];
            a3 += a * wrow[3];
        }
    }
    f32x4* wout = (f32x4*)ic_ws + gid * 4;
    wout[0] = a0; wout[1] = a1; wout[2] = a2; wout[3] = a3;
}

// ================= Kernel B: greedy search =================
// Round-6's (passing) search phase: 2 lanes/row, ic loaded from ws.
// No projection load-balloon -> pressure ~180 < 256.
__global__ __launch_bounds__(NT, 1)
void search_kernel(const float* __restrict__ user_intent,
                   const float* __restrict__ ic_ws,
                   const float* __restrict__ W_k,
                   const float* __restrict__ b_k,
                   float* __restrict__ out)
{
    __shared__ f32x4 s_wk[H * 4];
    __shared__ f32x4 s_bk[4];
    __shared__ f32x4 s_out[RPB * RQ];   // 50 KB out staging
    {
        float* wkf = (float*)s_wk;
        for (int i = threadIdx.x; i < H * H; i += NT) wkf[i] = W_k[i];
        if (threadIdx.x < H) ((float*)s_bk)[threadIdx.x] = b_k[threadIdx.x];
    }
    __syncthreads();

    const int t = threadIdx.x;
    const int half = t & 1;
    const int r = t >> 1;
    const size_t b = (size_t)blockIdx.x * RPB + r;

    // Load this lane's 5 ic rows: 320B contiguous per lane.
    const f32x4* icin = (const f32x4*)ic_ws + (b * S + half * SL) * 4;
    f32x4 ic[SL][4];
    #pragma unroll
    for (int ls = 0; ls < SL; ++ls)
        #pragma unroll
        for (int q = 0; q < 4; ++q)
            ic[ls][q] = icin[ls * 4 + q];

    const f32x4* urow = (const f32x4*)user_intent + b * 4;
    f32x4 usum[4];
    #pragma unroll
    for (int q = 0; q < 4; ++q) {
        usum[q] = urow[q];
        if (!half) s_out[r * RQ + q] = usum[q];   // ui[:,0,:]
    }

    for (int it = 0; it < NITER; ++it) {
        // ic = ic @ Wk + bk, in place per row (k ascending)
        #pragma unroll
        for (int ls = 0; ls < SL; ++ls) {
            f32x4 n0 = s_bk[0], n1 = s_bk[1], n2 = s_bk[2], n3 = s_bk[3];
            #pragma unroll
            for (int k = 0; k < H; ++k) {
                float a = ic[ls][k >> 2][k & 3];
                const f32x4* wrow = &s_wk[k * 4];
                n0 += a * wrow[0];
                n1 += a * wrow[1];
                n2 += a * wrow[2];
                n3 += a * wrow[3];
            }
            ic[ls][0] = n0; ic[ls][1] = n1; ic[ls][2] = n2; ic[ls][3] = n3;
        }

        float cnt = (float)(it + 1);
        f32x4 src[4];
        #pragma unroll
        for (int q = 0; q < 4; ++q) src[q] = usum[q] / cnt;

        float best = 0.0f;
        int gidx = half * SL;
        #pragma unroll
        for (int ls = 0; ls < SL; ++ls) {
            float sc = 0.0f;
            #pragma unroll
            for (int q = 0; q < 4; ++q)
                #pragma unroll
                for (int c = 0; c < 4; ++c)
                    sc += ic[ls][q][c] * src[q][c];
            if (ls == 0 || sc > best) { best = sc; gidx = half * SL + ls; }
        }

        // pair combine: low half wins ties (first-max over s)
        float osc = __shfl_xor(best, 1);
        int oidx = __shfl_xor(gidx, 1);
        float scL = half ? osc : best;
        int   iL  = half ? oidx : gidx;
        float scH = half ? best : osc;
        int   iH  = half ? gidx : oidx;
        int bidx = (scH > scL) ? iH : iL;

        f32x4 ivl[4];
        #pragma unroll
        for (int q = 0; q < 4; ++q) ivl[q] = f32x4{0.f, 0.f, 0.f, 0.f};
        #pragma unroll
        for (int ls = 0; ls < SL; ++ls) {
            bool take = ((half * SL + ls) == bidx);
            #pragma unroll
            for (int q = 0; q < 4; ++q)
                ivl[q] = take ? ic[ls][q] : ivl[q];
        }
        f32x4 iv[4];
        #pragma unroll
        for (int q = 0; q < 4; ++q) {
            #pragma unroll
            for (int c = 0; c < 4; ++c)
                iv[q][c] = ivl[q][c] + __shfl_xor(ivl[q][c], 1);
        }

        #pragma unroll
        for (int q = 0; q < 4; ++q) {
            usum[q] += iv[q];
            if (!half) s_out[r * RQ + (it + 1) * 4 + q] = iv[q];
        }
    }

    __syncthreads();
    f32x4* out4 = (f32x4*)out;
    const size_t obase = (size_t)blockIdx.x * RPB * OUTQ;
    #pragma unroll
    for (int k = 0; k < OUTQ / 2; ++k) {
        int j = t + k * NT;
        int row = j / OUTQ;
        int q = j - row * OUTQ;
        out4[obase + j] = s_out[row * RQ + q];
    }
}

// ================= Fallback: round-5 fused kernel (known-good 301us) =====
__global__ __launch_bounds__(NT, 1)
void fused_kernel(const float* __restrict__ user_intent,
                  const float* __restrict__ item_corpus,
                  const float* __restrict__ W_proj,
                  const float* __restrict__ b_proj,
                  const float* __restrict__ W_k,
                  const float* __restrict__ b_k,
                  float* __restrict__ out)
{
    __shared__ f32x4 s_wp[D * 4];
    __shared__ f32x4 s_wk[H * 4];
    __shared__ f32x4 s_bp[4];
    __shared__ f32x4 s_bk[4];
    __shared__ f32x4 s_out[NT * RQ];
    {
        float* wpf = (float*)s_wp;
        for (int i = threadIdx.x; i < D * H; i += NT) wpf[i] = W_proj[i];
        float* wkf = (float*)s_wk;
        for (int i = threadIdx.x; i < H * H; i += NT) wkf[i] = W_k[i];
        if (threadIdx.x < H) {
            ((float*)s_bp)[threadIdx.x] = b_proj[threadIdx.x];
            ((float*)s_bk)[threadIdx.x] = b_k[threadIdx.x];
        }
    }
    __syncthreads();

    const int t = threadIdx.x;
    const size_t b = (size_t)blockIdx.x * NT + t;
    const f32x4* crow = (const f32x4*)item_corpus + b * (S * D / 4);
    const f32x4* urow = (const f32x4*)user_intent + b * 4;
    f32x4 usum[4];
    #pragma unroll
    for (int q = 0; q < 4; ++q) {
        f32x4 u = urow[q];
        usum[q] = u;
        s_out[t * RQ + q] = u;
    }
    f32x4 ic[S][4];
    #pragma unroll
    for (int s = 0; s < S; ++s) {
        f32x4 a0 = s_bp[0], a1 = s_bp[1], a2 = s_bp[2], a3 = s_bp[3];
        #pragma unroll 5
        for (int i = 0; i < D / 4; ++i) {
            f32x4 c = crow[s * (D / 4) + i];
            #pragma unroll
            for (int dd = 0; dd < 4; ++dd) {
                float a = c[dd];
                const f32x4* wrow = &s_wp[(i * 4 + dd) * 4];
                a0 += a * wrow[0]; a1 += a * wrow[1];
                a2 += a * wrow[2]; a3 += a * wrow[3];
            }
        }
        ic[s][0] = a0; ic[s][1] = a1; ic[s][2] = a2; ic[s][3] = a3;
    }
    for (int it = 0; it < NITER; ++it) {
        #pragma unroll
        for (int s = 0; s < S; ++s) {
            f32x4 n0 = s_bk[0], n1 = s_bk[1], n2 = s_bk[2], n3 = s_bk[3];
            #pragma unroll
            for (int k = 0; k < H; ++k) {
                float a = ic[s][k >> 2][k & 3];
                const f32x4* wrow = &s_wk[k * 4];
                n0 += a * wrow[0]; n1 += a * wrow[1];
                n2 += a * wrow[2]; n3 += a * wrow[3];
            }
            ic[s][0] = n0; ic[s][1] = n1; ic[s][2] = n2; ic[s][3] = n3;
        }
        float cnt = (float)(it + 1);
        f32x4 src[4];
        #pragma unroll
        for (int q = 0; q < 4; ++q) src[q] = usum[q] / cnt;
        float best = 0.0f;
        int bidx = 0;
        #pragma unroll
        for (int s = 0; s < S; ++s) {
            float sc = 0.0f;
            #pragma unroll
            for (int q = 0; q < 4; ++q)
                #pragma unroll
                for (int c = 0; c < 4; ++c)
                    sc += ic[s][q][c] * src[q][c];
            if (s == 0 || sc > best) { best = sc; bidx = s; }
        }
        f32x4 iv[4];
        #pragma unroll
        for (int q = 0; q < 4; ++q) iv[q] = ic[0][q];
        #pragma unroll
        for (int s = 1; s < S; ++s) {
            bool take = (bidx == s);
            #pragma unroll
            for (int q = 0; q < 4; ++q)
                iv[q] = take ? ic[s][q] : iv[q];
        }
        #pragma unroll
        for (int q = 0; q < 4; ++q) {
            usum[q] += iv[q];
            s_out[t * RQ + (it + 1) * 4 + q] = iv[q];
        }
    }
    __syncthreads();
    f32x4* out4 = (f32x4*)out;
    const size_t obase = (size_t)blockIdx.x * NT * OUTQ;
    #pragma unroll
    for (int k = 0; k < OUTQ; ++k) {
        int j = t + k * NT;
        int row = j / OUTQ;
        int q = j - row * OUTQ;
        out4[obase + j] = s_out[row * RQ + q];
    }
}

extern "C" void kernel_launch(void* const* d_in, const int* in_sizes, int n_in,
                              void* d_out, int out_size, void* d_ws, size_t ws_size,
                              hipStream_t stream) {
    const float* user_intent = (const float*)d_in[0];
    const float* item_corpus = (const float*)d_in[1];
    const float* W_proj      = (const float*)d_in[2];
    const float* b_proj      = (const float*)d_in[3];
    const float* W_k         = (const float*)d_in[4];
    const float* b_k         = (const float*)d_in[5];
    float* out = (float*)d_out;
    const int bs = 65536;

    if (ws_size >= WS_NEEDED) {
        float* ic_ws = (float*)d_ws;
        hipLaunchKernelGGL(proj_kernel,
                           dim3(bs * S / NT), dim3(NT), 0, stream,
                           item_corpus, W_proj, b_proj, ic_ws);
        hipLaunchKernelGGL(search_kernel,
                           dim3(bs / RPB), dim3(NT), 0, stream,
                           user_intent, ic_ws, W_k, b_k, out);
    } else {
        hipLaunchKernelGGL(fused_kernel,
                           dim3(bs / NT), dim3(NT), 0, stream,
                           user_intent, item_corpus, W_proj, b_proj, W_k, b_k, out);
    }
}